// Round 1
// baseline (185.528 us; speedup 1.0000x reference)
//
#include <hip/hip_runtime.h>
#include <hip/hip_bf16.h>
#include <math.h>

#define B_ 8
#define T_ 2048
#define E_ 1024
#define H_ 128
#define M_ (B_*T_)              // 16384
#define SCALE_ 45.25483399593904f   // sqrt(2048) per reference
#define SEG_ 4                      // key-range split factor for attention

typedef __attribute__((ext_vector_type(8))) short bf16x8;
typedef __attribute__((ext_vector_type(4))) float f32x4;

#define mfma16(A, Bv, C) __builtin_amdgcn_mfma_f32_16x16x32_bf16((A), (Bv), (C), 0, 0, 0)

// ---- fragment-order flat indices (ushort elements) -------------------------
// Shared by producer AND consumer to avoid index-mismatch bugs (r2/r4 class).
// lane = quad*16 + l15 throughout.
// W-frag (proj B operand): g = mat*8+nt (0..23), kc = k/32 (0..31);
//   element (n = (g&7)*16 + l15, k = kc*32 + quad*8 + j)
#define FRAGW(g, kc, lane)  ((((size_t)(g)*32 + (kc))*64 + (lane))*8)
// K-frag (attn QK B operand): kt16 = key/16 (0..127), kc = h/32 (0..3);
//   element (key = kt16*16 + l15, h = kc*32 + quad*8 + j)
#define FRAGK(b, kt16, kc, lane) (((((size_t)(b)*128 + (kt16))*4 + (kc))*64 + (lane))*8)
// V-frag (attn PV B operand): ht = h/16 (0..7), kt32 = key/32 (0..63);
//   element (h = ht*16 + l15, key = kt32*32 + quad*8 + j)
#define FRAGV(b, ht, kt32, lane) (((((size_t)(b)*8 + (ht))*64 + (kt32))*64 + (lane))*8)

__device__ __forceinline__ ushort bf16_rne(float f) {
  unsigned u = __float_as_uint(f);
  u += 0x7fffu + ((u >> 16) & 1u);
  return (ushort)(u >> 16);
}
__device__ __forceinline__ float bf16_tof(ushort h) {
  return __uint_as_float(((unsigned)h) << 16);
}

// DPP row_ror:N within 16-lane rows; rotate-reduce leaves result in all lanes.
template <int N>
__device__ __forceinline__ float ror16(float x) {
  return __uint_as_float((unsigned)__builtin_amdgcn_update_dpp(
      0, (int)__float_as_uint(x), 0x120 + N, 0xF, 0xF, true));
}
__device__ __forceinline__ float rowmax16(float x) {
  x = fmaxf(x, ror16<8>(x));
  x = fmaxf(x, ror16<4>(x));
  x = fmaxf(x, ror16<2>(x));
  x = fmaxf(x, ror16<1>(x));
  return x;
}
__device__ __forceinline__ float rowsum16(float x) {
  x += ror16<8>(x);
  x += ror16<4>(x);
  x += ror16<2>(x);
  x += ror16<1>(x);
  return x;
}

// ---------------------------------------------------------------------------
// Kernel 0: split W -> whT/wlT bf16 in PROJ-B FRAGMENT ORDER.
// thread idx enumerates (mat, nt, kc, lane) chunks; writes coalesced.
// ---------------------------------------------------------------------------
__global__ __launch_bounds__(256) void wsplit(
    const float* __restrict__ Wq, const float* __restrict__ Wk,
    const float* __restrict__ Wv,
    ushort* __restrict__ whT, ushort* __restrict__ wlT)
{
  const int idx  = blockIdx.x * 256 + threadIdx.x;  // 0..49151
  const int mat  = idx >> 14;                       // 16384 chunks per mat
  const int rem  = idx & 16383;
  const int nt   = rem >> 11;                       // 0..7
  const int kc   = (rem >> 6) & 31;                 // 0..31
  const int lane = rem & 63;
  const int quad = lane >> 4, l15 = lane & 15;
  const float* W = (mat == 0) ? Wq : (mat == 1) ? Wk : Wv;
  const int n  = nt * 16 + l15;
  const int k0 = kc * 32 + quad * 8;
  bf16x8 hv, lv;
  #pragma unroll
  for (int j = 0; j < 8; ++j) {
    const float f = W[(size_t)(k0 + j) * H_ + n];
    const ushort h = bf16_rne(f);
    hv[j] = (short)h;
    lv[j] = (short)bf16_rne(f - bf16_tof(h));
  }
  *(bf16x8*)(whT + (size_t)idx * 8) = hv;   // == FRAGW(mat*8+nt, kc, lane)
  *(bf16x8*)(wlT + (size_t)idx * 8) = lv;
}

// ---------------------------------------------------------------------------
// Kernel 1: fused QKV projection, round-8:
//  * B fragments loaded GLOBAL->REG from fragment-ordered whT/wlT, double-
//    buffered across k — no B LDS at all (r7: 7.57e6 LDS conflict cycles).
//  * A (x, split on the fly) in fragment-order LDS: frag reads 2-way (free),
//    writes 4-way on only 2 ops/thread/iter.
//  * epilogues emit q [t][h]; k in attn-K fragment order; v in attn-V
//    fragment order (via LDS transpose, stride 72 for alignment).
// Block: 64 m-rows x 192 n-cols (half). grid (256, 2).
// ---------------------------------------------------------------------------
#define PSTEP(KC, BH, BL, BHN, BLN) do {                                      \
    __syncthreads();                                                          \
    {                                                                         \
      const float f_[8] = {xf0.x, xf0.y, xf0.z, xf0.w,                        \
                           xf1.x, xf1.y, xf1.z, xf1.w};                       \
      bf16x8 hv_, lv_;                                                        \
      _Pragma("unroll")                                                       \
      for (int jj_ = 0; jj_ < 8; ++jj_) {                                     \
        const ushort h_ = bf16_rne(f_[jj_]);                                  \
        hv_[jj_] = (short)h_;                                                 \
        lv_[jj_] = (short)bf16_rne(f_[jj_] - bf16_tof(h_));                   \
      }                                                                       \
      *(bf16x8*)&AhS[ca * 8] = hv_;                                           \
      *(bf16x8*)&AlS[ca * 8] = lv_;                                           \
    }                                                                         \
    __syncthreads();                                                          \
    if ((KC) + 1 < 32) {                                                      \
      const float* s_ = x + (size_t)(m0 + arow) * E_ + ((KC) + 1) * 32 + akoff;\
      xf0 = *(const float4*)s_;                                               \
      xf1 = *(const float4*)(s_ + 4);                                         \
      _Pragma("unroll")                                                       \
      for (int j_ = 0; j_ < 3; ++j_) {                                        \
        const int g_ = g0 + 4 * j_;                                           \
        BHN[j_] = *(const bf16x8*)(whT + FRAGW(g_, (KC) + 1, lane));          \
        if (g_ < 16)                                                          \
          BLN[j_] = *(const bf16x8*)(wlT + FRAGW(g_, (KC) + 1, lane));        \
      }                                                                       \
    }                                                                         \
    bf16x8 a_h_[4], a_l_[4];                                                  \
    _Pragma("unroll")                                                         \
    for (int mt_ = 0; mt_ < 4; ++mt_) {                                       \
      a_h_[mt_] = *(const bf16x8*)&AhS[(((mt_ * 4 + quad) * 16) + l15) * 8];  \
      a_l_[mt_] = *(const bf16x8*)&AlS[(((mt_ * 4 + quad) * 16) + l15) * 8];  \
    }                                                                         \
    _Pragma("unroll")                                                         \
    for (int j_ = 0; j_ < 3; ++j_) {                                          \
      const int g_ = g0 + 4 * j_;                                             \
      if (g_ < 16) {                                                          \
        _Pragma("unroll")                                                     \
        for (int mt_ = 0; mt_ < 4; ++mt_) {                                   \
          acc[j_][mt_] = mfma16(a_h_[mt_], BH[j_], acc[j_][mt_]);             \
          acc[j_][mt_] = mfma16(a_h_[mt_], BL[j_], acc[j_][mt_]);             \
          acc[j_][mt_] = mfma16(a_l_[mt_], BH[j_], acc[j_][mt_]);             \
        }                                                                     \
      } else {                                                                \
        _Pragma("unroll")                                                     \
        for (int mt_ = 0; mt_ < 4; ++mt_)                                     \
          acc[j_][mt_] = mfma16(a_h_[mt_], BH[j_], acc[j_][mt_]);             \
      }                                                                       \
    }                                                                         \
  } while (0)

__global__ __launch_bounds__(256) void proj_fused(
    const float* __restrict__ x,
    const ushort* __restrict__ whT, const ushort* __restrict__ wlT,
    ushort* __restrict__ qh, ushort* __restrict__ ql,
    ushort* __restrict__ kfh, ushort* __restrict__ kfl,
    ushort* __restrict__ vF)
{
  const int m0   = blockIdx.x * 64;
  const int half = blockIdx.y;
  const int tid  = threadIdx.x;
  const int wave = tid >> 6, lane = tid & 63;
  const int quad = lane >> 4, l15 = lane & 15;

  __shared__ __align__(16) ushort SM[9216];    // A frags (4096) / smT (9216)
  ushort* AhS = SM;            // fragment order: chunk (mt*4+kq)*16+l15m
  ushort* AlS = SM + 2048;

  f32x4 acc[3][4];
  #pragma unroll
  for (int j = 0; j < 3; ++j)
    #pragma unroll
    for (int mt = 0; mt < 4; ++mt) acc[j][mt] = (f32x4){0.f, 0.f, 0.f, 0.f};

  const int arow  = tid >> 2;          // 0..63
  const int akoff = (tid & 3) * 8;     // 0,8,16,24
  const int ca    = ((arow >> 4) * 4 + (tid & 3)) * 16 + (arow & 15);
  const int g0    = half * 12 + wave;  // wave's n-tiles: g0, g0+4, g0+8

  float4 xf0, xf1;
  bf16x8 bhA[3], blA[3], bhB[3], blB[3];
  {
    const float* s = x + (size_t)(m0 + arow) * E_ + akoff;
    xf0 = *(const float4*)s;
    xf1 = *(const float4*)(s + 4);
    #pragma unroll
    for (int j = 0; j < 3; ++j) {
      const int g = g0 + 4 * j;
      bhA[j] = *(const bf16x8*)(whT + FRAGW(g, 0, lane));
      if (g < 16) blA[j] = *(const bf16x8*)(wlT + FRAGW(g, 0, lane));
    }
  }

  int kc = 0;
  while (true) {
    PSTEP(kc, bhA, blA, bhB, blB); if (++kc == 32) break;
    PSTEP(kc, bhB, blB, bhA, blA); if (++kc == 32) break;
  }

  // ---- epilogue: q -> [t][h]; k -> attn-K fragment order ----
  #pragma unroll
  for (int j = 0; j < 3; ++j) {
    const int g = g0 + 4 * j;
    if (g < 8) {                               // q
      const int ncol = g * 16 + l15;
      #pragma unroll
      for (int mt = 0; mt < 4; ++mt)
        #pragma unroll
        for (int r = 0; r < 4; ++r) {
          const float a = acc[j][mt][r];
          const ushort h = bf16_rne(a);
          const size_t off = (size_t)(m0 + mt * 16 + quad * 4 + r) * H_ + ncol;
          qh[off] = h;
          ql[off] = bf16_rne(a - bf16_tof(h));
        }
    } else if (g < 16) {                       // k -> fragment order
      const int hcol = (g - 8) * 16 + l15;
      const int kch  = hcol >> 5;
      const int qdh  = (hcol >> 3) & 3;
      const int jj   = hcol & 7;
      #pragma unroll
      for (int mt = 0; mt < 4; ++mt)
        #pragma unroll
        for (int r = 0; r < 4; ++r) {
          const float a = acc[j][mt][r];
          const int tg = m0 + mt * 16 + quad * 4 + r;
          const int bb = tg >> 11, tl = tg & 2047;
          const size_t ad = FRAGK(bb, tl >> 4, kch, qdh * 16 + (tl & 15)) + jj;
          const ushort h = bf16_rne(a);
          kfh[ad] = h;
          kfl[ad] = bf16_rne(a - bf16_tof(h));
        }
    }
  }
  // ---- epilogue: v (half 1) -> attn-V fragment order via LDS transpose ----
  if (half == 1) {
    __syncthreads();
    ushort* smT = SM;                          // [128][72] (72: 16B-aligned rows)
    #pragma unroll
    for (int j = 1; j < 3; ++j) {              // g = 16..23
      const int g = 12 + wave + 4 * j;
      const int hcol = (g - 16) * 16 + l15;
      #pragma unroll
      for (int mt = 0; mt < 4; ++mt)
        #pragma unroll
        for (int r = 0; r < 4; ++r)
          smT[hcol * 72 + mt * 16 + quad * 4 + r] = bf16_rne(acc[j][mt][r]);
    }
    __syncthreads();
    const int bb = m0 >> 11, t0 = m0 & 2047;
    #pragma unroll
    for (int u = 0; u < 4; ++u) {
      const int c   = u * 256 + tid;           // 1024 = 8 ht x 2 ktl x 64 lane
      const int ht  = c >> 7;
      const int ktl = (c >> 6) & 1;
      const int lv  = c & 63;
      const int qv  = lv >> 4, l15v = lv & 15;
      *(bf16x8*)(vF + FRAGV(bb, ht, (t0 >> 5) + ktl, lv)) =
          *(const bf16x8*)&smT[(ht * 16 + l15v) * 72 + ktl * 32 + qv * 8];
    }
  }
}

// ---------------------------------------------------------------------------
// Kernel 2: block flash attention, split-K (logic identical to passing r7;
// staging rewired to fragment-order inputs -> LINEAR LDS copies, conflict-
// free b128 reads/writes; LDS 29 KB -> 5 blocks/CU).
// ---------------------------------------------------------------------------
__global__ __launch_bounds__(256) void attn_flash(
    const ushort* __restrict__ qh, const ushort* __restrict__ ql,
    const ushort* __restrict__ kfh, const ushort* __restrict__ kfl,
    const ushort* __restrict__ vF,
    ushort* __restrict__ Opart, float* __restrict__ mlpart)
{
  const int b    = (int)blockIdx.x & 7;        // %8 -> XCD pin
  const int seg  = (int)blockIdx.x >> 3;
  const int qt   = 31 - (int)blockIdx.y;       // heavy first
  const int q0   = qt * 64;
  const int tid  = threadIdx.x;
  const int wave = tid >> 6, lane = tid & 63;
  const int quad = lane >> 4, l15 = lane & 15;
  const f32x4 z4 = (f32x4){0.f, 0.f, 0.f, 0.f};

  __shared__ __align__(16) ushort KhS[4096];   // [s(2)][kc(4)][lane][8] linear
  __shared__ __align__(16) ushort KlS[4096];
  __shared__ __align__(16) ushort VtS[4096];   // [ht(8)][lane][8] linear
  __shared__ __align__(16) ushort smP[4 * 640];

  const int ntiles = 2 * qt + 2;
  const int cnt    = (ntiles + SEG_ - 1) >> 2;
  const int jt0    = seg * cnt;
  const int jt1    = (jt0 + cnt < ntiles) ? (jt0 + cnt) : ntiles;

  const int q0w = q0 + wave * 16;
  const int ntw = ((q0w + 15) >> 5) + 1;
  const size_t pidx = ((size_t)(b * 128 + qt * 4 + wave)) * SEG_ + seg;
  ushort* op = Opart + pidx * 2048;
  float*  ml = mlpart + pidx * 32;

  if (jt0 >= jt1) {
    const bf16x8 zz = {0, 0, 0, 0, 0, 0, 0, 0};
    #pragma unroll
    for (int u = 0; u < 4; ++u)
      *(bf16x8*)(op + lane * 32 + u * 8) = zz;
    if (lane < 32) ml[lane] = (lane & 1) ? 0.f : -1e30f;
    return;
  }

  const size_t base = (size_t)b * T_ * H_;

  const ushort* qhp = qh + base + (size_t)(q0w + l15) * H_ + quad * 8;
  const ushort* qlp = ql + base + (size_t)(q0w + l15) * H_ + quad * 8;
  bf16x8 Qh[4], Ql[4];
  #pragma unroll
  for (int c = 0; c < 4; ++c) {
    Qh[c] = *(const bf16x8*)(qhp + c * 32);
    Ql[c] = *(const bf16x8*)(qlp + c * 32);
  }

  f32x4 O[8];
  #pragma unroll
  for (int i = 0; i < 8; ++i) O[i] = z4;
  float mstate[4] = {-1e30f, -1e30f, -1e30f, -1e30f};
  float lstate[4] = {0.f, 0.f, 0.f, 0.f};

  // staging regs; chunk c: K: (s = c>>8, kc = (c>>6)&3, lane_k = c&63)
  //               V: (ht = c>>6, lane_v = c&63)
  bf16x8 rkh[2], rkl[2], rv[2];
  {
    #pragma unroll
    for (int u = 0; u < 2; ++u) {
      const int c = u * 256 + tid;
      rkh[u] = *(const bf16x8*)(kfh + FRAGK(b, 2 * jt0 + (c >> 8), (c >> 6) & 3, c & 63));
      rkl[u] = *(const bf16x8*)(kfl + FRAGK(b, 2 * jt0 + (c >> 8), (c >> 6) & 3, c & 63));
      rv[u]  = *(const bf16x8*)(vF  + FRAGV(b, c >> 6, jt0, c & 63));
    }
  }

  for (int jt = jt0; jt < jt1; ++jt) {
    __syncthreads();
    #pragma unroll
    for (int u = 0; u < 2; ++u) {
      const int c = u * 256 + tid;
      *(bf16x8*)&KhS[c * 8] = rkh[u];
      *(bf16x8*)&KlS[c * 8] = rkl[u];
      *(bf16x8*)&VtS[c * 8] = rv[u];
    }
    __syncthreads();

    if (jt + 1 < jt1) {
      #pragma unroll
      for (int u = 0; u < 2; ++u) {
        const int c = u * 256 + tid;
        rkh[u] = *(const bf16x8*)(kfh + FRAGK(b, 2 * (jt + 1) + (c >> 8), (c >> 6) & 3, c & 63));
        rkl[u] = *(const bf16x8*)(kfl + FRAGK(b, 2 * (jt + 1) + (c >> 8), (c >> 6) & 3, c & 63));
        rv[u]  = *(const bf16x8*)(vF  + FRAGV(b, c >> 6, jt + 1, c & 63));
      }
    }

    if (jt < ntw) {
      const int k0 = jt * 32;
      f32x4 shh0 = z4, shh1 = z4, sx0 = z4, sx1 = z4;
      #pragma unroll
      for (int c = 0; c < 4; ++c) {
        const bf16x8 kh0 = *(const bf16x8*)&KhS[(c * 64 + lane) * 8];
        const bf16x8 kh1 = *(const bf16x8*)&KhS[((4 + c) * 64 + lane) * 8];
        const bf16x8 kl0 = *(const bf16x8*)&KlS[(c * 64 + lane) * 8];
        const bf16x8 kl1 = *(const bf16x8*)&KlS[((4 + c) * 64 + lane) * 8];
        shh0 = mfma16(Qh[c], kh0, shh0);
        shh1 = mfma16(Qh[c], kh1, shh1);
        sx0  = mfma16(Qh[c], kl0, sx0);
        sx1  = mfma16(Qh[c], kl1, sx1);
        sx0  = mfma16(Ql[c], kh0, sx0);
        sx1  = mfma16(Ql[c], kh1, sx1);
      }

      float s0[4], s1[4];
      #pragma unroll
      for (int r = 0; r < 4; ++r) {
        s0[r] = (shh0[r] + sx0[r]) * SCALE_;
        s1[r] = (shh1[r] + sx1[r]) * SCALE_;
      }
      if (jt == ntw - 1) {
        const int krel0 = k0 + l15      - q0w - quad * 4;
        const int krel1 = k0 + 16 + l15 - q0w - quad * 4;
        #pragma unroll
        for (int r = 0; r < 4; ++r) {
          if (krel0 > r) s0[r] = -1e30f;
          if (krel1 > r) s1[r] = -1e30f;
        }
      }

      float alpha[4];
      #pragma unroll
      for (int r = 0; r < 4; ++r) {
        const float rm   = rowmax16(fmaxf(s0[r], s1[r]));
        const float mnew = fmaxf(mstate[r], rm);
        alpha[r] = __expf(mstate[r] - mnew);
        mstate[r] = mnew;
        const float p0 = __expf(s0[r] - mnew);
        const float p1 = __expf(s1[r] - mnew);
        lstate[r] = lstate[r] * alpha[r] + rowsum16(p0 + p1);
        smP[wave * 640 + (quad * 4 + r) * 40 + l15]      = bf16_rne(p0);
        smP[wave * 640 + (quad * 4 + r) * 40 + 16 + l15] = bf16_rne(p1);
      }
      #pragma unroll
      for (int ct = 0; ct < 8; ++ct) {
        O[ct][0] *= alpha[0]; O[ct][1] *= alpha[1];
        O[ct][2] *= alpha[2]; O[ct][3] *= alpha[3];
      }
      const bf16x8 pA = *(const bf16x8*)&smP[wave * 640 + l15 * 40 + quad * 8];
      #pragma unroll
      for (int ct = 0; ct < 8; ++ct) {
        const bf16x8 vf = *(const bf16x8*)&VtS[(ct * 64 + lane) * 8];
        O[ct] = mfma16(pA, vf, O[ct]);
      }
    }
  }

  #pragma unroll
  for (int r = 0; r < 4; ++r)
    #pragma unroll
    for (int ct = 0; ct < 8; ++ct)
      op[(quad * 4 + r) * 128 + ct * 16 + l15] = bf16_rne(O[ct][r]);
  if (l15 == 0) {
    #pragma unroll
    for (int r = 0; r < 4; ++r) {
      ml[(quad * 4 + r) * 2]     = mstate[r];
      ml[(quad * 4 + r) * 2 + 1] = lstate[r];
    }
  }
}

// ---------------------------------------------------------------------------
// Kernel 3: combine 4 split-K partials per q-row (unchanged).
// ---------------------------------------------------------------------------
__global__ __launch_bounds__(256) void attn_combine(
    const ushort* __restrict__ Opart, const float* __restrict__ mlpart,
    float* __restrict__ out)
{
  const int idx = blockIdx.x * 256 + threadIdx.x;
  const int c4  = idx & 31;
  const int r   = idx >> 5;
  const int t   = r & 2047;
  const int qt  = t >> 4, r16 = t & 15;
  const size_t pb = ((size_t)((r >> 11) * 128 + qt)) * SEG_;

  float m[SEG_], l[SEG_];
  #pragma unroll
  for (int s = 0; s < SEG_; ++s) {
    m[s] = mlpart[(pb + s) * 32 + r16 * 2];
    l[s] = mlpart[(pb + s) * 32 + r16 * 2 + 1];
  }
  float M = m[0];
  #pragma unroll
  for (int s = 1; s < SEG_; ++s) M = fmaxf(M, m[s]);
  float w[SEG_], L = 0.f;
  #pragma unroll
  for (int s = 0; s < SEG_; ++s) {
    w[s] = __expf(m[s] - M);
    L += l[s] * w[s];
  }
  float4 acc = make_float4(0.f, 0.f, 0.f, 0.f);
  #pragma unroll
  for (int s = 0; s < SEG_; ++s) {
    const ushort4 o = *(const ushort4*)(Opart + (pb + s) * 2048 + r16 * 128 + c4 * 4);
    acc.x += w[s] * bf16_tof(o.x);
    acc.y += w[s] * bf16_tof(o.y);
    acc.z += w[s] * bf16_tof(o.z);
    acc.w += w[s] * bf16_tof(o.w);
  }
  const float inv = 1.0f / L;
  *(float4*)(out + (size_t)r * H_ + c4 * 4) =
      make_float4(acc.x * inv, acc.y * inv, acc.z * inv, acc.w * inv);
}

// ---------------------------------------------------------------------------
extern "C" void kernel_launch(void* const* d_in, const int* in_sizes, int n_in,
                              void* d_out, int out_size, void* d_ws, size_t ws_size,
                              hipStream_t stream) {
  (void)in_sizes; (void)n_in; (void)out_size; (void)ws_size;
  const float* x  = (const float*)d_in[0];
  const float* Wq = (const float*)d_in[1];
  const float* Wk = (const float*)d_in[2];
  const float* Wv = (const float*)d_in[3];
  float* out = (float*)d_out;

  // ws layout identical sizes to r7 (~39.9 MB), contents re-ordered:
  //   qh, ql            : M_*H_ each, [t][h]
  //   kfh, kfl          : M_*H_ each, attn-K fragment order
  //   vF                : M_*H_, attn-V fragment order
  //   whT, wlT          : 3*H_*E_ each, proj-B fragment order
  //   Opart, mlpart     : split-K partials
  ushort* qhb = (ushort*)d_ws;
  ushort* qlb = qhb + (size_t)M_ * H_;
  ushort* kfh = qlb + (size_t)M_ * H_;
  ushort* kfl = kfh + (size_t)M_ * H_;
  ushort* vFb = kfl + (size_t)M_ * H_;
  ushort* whT = vFb + (size_t)M_ * H_;
  ushort* wlT = whT + (size_t)3 * H_ * E_;
  ushort* Opart = wlT + (size_t)3 * H_ * E_;
  float*  mlpart = (float*)(Opart + (size_t)B_ * 128 * SEG_ * 2048);

  wsplit<<<dim3(192), 256, 0, stream>>>(Wq, Wk, Wv, whT, wlT);
  proj_fused<<<dim3(M_/64, 2), 256, 0, stream>>>(x, whT, wlT,
                                                 qhb, qlb, kfh, kfl, vFb);
  attn_flash<<<dim3(B_*SEG_, 32), 256, 0, stream>>>(qhb, qlb, kfh, kfl, vFb,
                                                    Opart, mlpart);
  attn_combine<<<dim3(2048), 256, 0, stream>>>(Opart, mlpart, out);
}

// Round 2
// 177.709 us; speedup vs baseline: 1.0440x; 1.0440x over previous
//
#include <hip/hip_runtime.h>
#include <hip/hip_bf16.h>
#include <math.h>

#define B_ 8
#define T_ 2048
#define E_ 1024
#define H_ 128
#define M_ (B_*T_)              // 16384
#define SCALE_ 45.25483399593904f   // sqrt(2048) per reference
#define SEG_ 4                      // key-range split factor for attention

typedef __attribute__((ext_vector_type(8))) short bf16x8;
typedef __attribute__((ext_vector_type(4))) float f32x4;

#define mfma16(A, Bv, C) __builtin_amdgcn_mfma_f32_16x16x32_bf16((A), (Bv), (C), 0, 0, 0)

// ---- fragment-order flat indices (ushort elements) -------------------------
// lane = quad*16 + l15 throughout.
// W-frag (proj B operand): g = mat*8+nt (0..23), kc = k/32 (0..31);
//   element (n = (g&7)*16 + l15, k = kc*32 + quad*8 + j)
#define FRAGW(g, kc, lane)  ((((size_t)(g)*32 + (kc))*64 + (lane))*8)
// K-frag (attn QK B operand): kt16 = key/16 (0..127), kc = h/32 (0..3);
//   element (key = kt16*16 + l15, h = kc*32 + quad*8 + j)
#define FRAGK(b, kt16, kc, lane) (((((size_t)(b)*128 + (kt16))*4 + (kc))*64 + (lane))*8)
// V-frag (attn PV B operand): ht = h/16 (0..7), kt32 = key/32 (0..63);
//   element (h = ht*16 + l15, key = kt32*32 + quad*8 + j)
#define FRAGV(b, ht, kt32, lane) (((((size_t)(b)*8 + (ht))*64 + (kt32))*64 + (lane))*8)

__device__ __forceinline__ ushort bf16_rne(float f) {
  unsigned u = __float_as_uint(f);
  u += 0x7fffu + ((u >> 16) & 1u);
  return (ushort)(u >> 16);
}
__device__ __forceinline__ float bf16_tof(ushort h) {
  return __uint_as_float(((unsigned)h) << 16);
}

// LDS-only barrier: drain DS ops (cross-wave LDS dependency) but leave
// register-destined global prefetches (vmcnt) in flight across the barrier.
__device__ __forceinline__ void lds_barrier() {
  asm volatile("s_waitcnt lgkmcnt(0)" ::: "memory");
  __builtin_amdgcn_s_barrier();
}

// DPP row_ror:N within 16-lane rows; rotate-reduce leaves result in all lanes.
template <int N>
__device__ __forceinline__ float ror16(float x) {
  return __uint_as_float((unsigned)__builtin_amdgcn_update_dpp(
      0, (int)__float_as_uint(x), 0x120 + N, 0xF, 0xF, true));
}
__device__ __forceinline__ float rowmax16(float x) {
  x = fmaxf(x, ror16<8>(x));
  x = fmaxf(x, ror16<4>(x));
  x = fmaxf(x, ror16<2>(x));
  x = fmaxf(x, ror16<1>(x));
  return x;
}
__device__ __forceinline__ float rowsum16(float x) {
  x += ror16<8>(x);
  x += ror16<4>(x);
  x += ror16<2>(x);
  x += ror16<1>(x);
  return x;
}

// ---------------------------------------------------------------------------
// Kernel 0: split W -> whT/wlT bf16 in PROJ-B FRAGMENT ORDER. (unchanged)
// ---------------------------------------------------------------------------
__global__ __launch_bounds__(256) void wsplit(
    const float* __restrict__ Wq, const float* __restrict__ Wk,
    const float* __restrict__ Wv,
    ushort* __restrict__ whT, ushort* __restrict__ wlT)
{
  const int idx  = blockIdx.x * 256 + threadIdx.x;  // 0..49151
  const int mat  = idx >> 14;                       // 16384 chunks per mat
  const int rem  = idx & 16383;
  const int nt   = rem >> 11;                       // 0..7
  const int kc   = (rem >> 6) & 31;                 // 0..31
  const int lane = rem & 63;
  const int quad = lane >> 4, l15 = lane & 15;
  const float* W = (mat == 0) ? Wq : (mat == 1) ? Wk : Wv;
  const int n  = nt * 16 + l15;
  const int k0 = kc * 32 + quad * 8;
  bf16x8 hv, lv;
  #pragma unroll
  for (int j = 0; j < 8; ++j) {
    const float f = W[(size_t)(k0 + j) * H_ + n];
    const ushort h = bf16_rne(f);
    hv[j] = (short)h;
    lv[j] = (short)bf16_rne(f - bf16_tof(h));
  }
  *(bf16x8*)(whT + (size_t)idx * 8) = hv;   // == FRAGW(mat*8+nt, kc, lane)
  *(bf16x8*)(wlT + (size_t)idx * 8) = lv;
}

// ---------------------------------------------------------------------------
// Kernel 1: fused QKV projection, round-9:
//  * A LDS double-buffered -> ONE barrier per k-step (was two).
//  * loop barriers are lgkmcnt-only raw s_barrier: global B/x prefetches
//    (reg-destined, same-wave consumed) stay in flight across barriers.
//  * g-tile assignment rebalanced: every wave = 2 qk-tiles (3-product) +
//    1 v-tile (1-product) = 28 MFMA/step (was 36 half0 / 20 half1).
//    j<2: g = half*8 + j*4 + wave  (half0 -> q, half1 -> k)
//    j=2: g = 16 + half*4 + wave   (v; both halves run v-epilogue on 64 cols)
// Block: 64 m-rows x 192 n-cols. grid (256, 2).
// ---------------------------------------------------------------------------
#define PSTEP2(KC, CUR, NXT, BHC, BLC, BHN, BLN) do {                         \
    bf16x8 a_h_[4], a_l_[4];                                                  \
    _Pragma("unroll")                                                         \
    for (int mt_ = 0; mt_ < 4; ++mt_) {                                       \
      a_h_[mt_] = *(const bf16x8*)                                            \
          &SM[(CUR)*4096 + (((mt_*4 + quad)*16) + l15)*8];                    \
      a_l_[mt_] = *(const bf16x8*)                                            \
          &SM[(CUR)*4096 + 2048 + (((mt_*4 + quad)*16) + l15)*8];             \
    }                                                                         \
    float4 nf0_, nf1_;                                                        \
    if ((KC) + 2 < 32) {                                                      \
      nf0_ = *(const float4*)(xrow + ((KC) + 2)*32);                          \
      nf1_ = *(const float4*)(xrow + ((KC) + 2)*32 + 4);                      \
    } else { nf0_ = xf0; nf1_ = xf1; }                                        \
    if ((KC) + 1 < 32) {                                                      \
      BHN[0] = *(const bf16x8*)(whT + FRAGW(gq,     (KC)+1, lane));           \
      BHN[1] = *(const bf16x8*)(whT + FRAGW(gq + 4, (KC)+1, lane));           \
      BHN[2] = *(const bf16x8*)(whT + FRAGW(gv,     (KC)+1, lane));           \
      BLN[0] = *(const bf16x8*)(wlT + FRAGW(gq,     (KC)+1, lane));           \
      BLN[1] = *(const bf16x8*)(wlT + FRAGW(gq + 4, (KC)+1, lane));           \
      const float f_[8] = {xf0.x, xf0.y, xf0.z, xf0.w,                        \
                           xf1.x, xf1.y, xf1.z, xf1.w};                       \
      bf16x8 hv_, lv_;                                                        \
      _Pragma("unroll")                                                       \
      for (int jj_ = 0; jj_ < 8; ++jj_) {                                     \
        const ushort h_ = bf16_rne(f_[jj_]);                                  \
        hv_[jj_] = (short)h_;                                                 \
        lv_[jj_] = (short)bf16_rne(f_[jj_] - bf16_tof(h_));                   \
      }                                                                       \
      *(bf16x8*)&SM[(NXT)*4096 + ca*8] = hv_;                                 \
      *(bf16x8*)&SM[(NXT)*4096 + 2048 + ca*8] = lv_;                          \
    }                                                                         \
    _Pragma("unroll")                                                         \
    for (int mt_ = 0; mt_ < 4; ++mt_) {                                       \
      acc[0][mt_] = mfma16(a_h_[mt_], BHC[0], acc[0][mt_]);                   \
      acc[0][mt_] = mfma16(a_h_[mt_], BLC[0], acc[0][mt_]);                   \
      acc[0][mt_] = mfma16(a_l_[mt_], BHC[0], acc[0][mt_]);                   \
      acc[1][mt_] = mfma16(a_h_[mt_], BHC[1], acc[1][mt_]);                   \
      acc[1][mt_] = mfma16(a_h_[mt_], BLC[1], acc[1][mt_]);                   \
      acc[1][mt_] = mfma16(a_l_[mt_], BHC[1], acc[1][mt_]);                   \
      acc[2][mt_] = mfma16(a_h_[mt_], BHC[2], acc[2][mt_]);                   \
    }                                                                         \
    xf0 = nf0_; xf1 = nf1_;                                                   \
    lds_barrier();                                                            \
  } while (0)

__global__ __launch_bounds__(256) void proj_fused(
    const float* __restrict__ x,
    const ushort* __restrict__ whT, const ushort* __restrict__ wlT,
    ushort* __restrict__ qh, ushort* __restrict__ ql,
    ushort* __restrict__ kfh, ushort* __restrict__ kfl,
    ushort* __restrict__ vF)
{
  const int m0   = blockIdx.x * 64;
  const int half = blockIdx.y;
  const int tid  = threadIdx.x;
  const int wave = tid >> 6, lane = tid & 63;
  const int quad = lane >> 4, l15 = lane & 15;

  __shared__ __align__(16) ushort SM[8192];  // A dbuf [2][Ah 2048|Al 2048] / smT

  f32x4 acc[3][4];
  #pragma unroll
  for (int j = 0; j < 3; ++j)
    #pragma unroll
    for (int mt = 0; mt < 4; ++mt) acc[j][mt] = (f32x4){0.f, 0.f, 0.f, 0.f};

  const int arow  = tid >> 2;          // 0..63
  const int akoff = (tid & 3) * 8;     // 0,8,16,24
  const int ca    = ((arow >> 4) * 4 + (tid & 3)) * 16 + (arow & 15);
  const int gq    = half * 8 + wave;   // qk tiles: gq (j=0), gq+4 (j=1)
  const int gv    = 16 + half * 4 + wave;  // v tile (j=2)

  const float* xrow = x + (size_t)(m0 + arow) * E_ + akoff;

  float4 xf0, xf1;                 // x floats for step kc+1
  bf16x8 bhA[3], blA[2], bhB[3], blB[2];

  // ---- prologue: A(0) -> buf0; prefetch xf(1), B(0) ----
  {
    const float4 f0 = *(const float4*)xrow;
    const float4 f1 = *(const float4*)(xrow + 4);
    const float f_[8] = {f0.x, f0.y, f0.z, f0.w, f1.x, f1.y, f1.z, f1.w};
    bf16x8 hv, lv;
    #pragma unroll
    for (int jj = 0; jj < 8; ++jj) {
      const ushort h = bf16_rne(f_[jj]);
      hv[jj] = (short)h;
      lv[jj] = (short)bf16_rne(f_[jj] - bf16_tof(h));
    }
    *(bf16x8*)&SM[ca * 8] = hv;
    *(bf16x8*)&SM[2048 + ca * 8] = lv;
    xf0 = *(const float4*)(xrow + 32);
    xf1 = *(const float4*)(xrow + 36);
    bhA[0] = *(const bf16x8*)(whT + FRAGW(gq,     0, lane));
    bhA[1] = *(const bf16x8*)(whT + FRAGW(gq + 4, 0, lane));
    bhA[2] = *(const bf16x8*)(whT + FRAGW(gv,     0, lane));
    blA[0] = *(const bf16x8*)(wlT + FRAGW(gq,     0, lane));
    blA[1] = *(const bf16x8*)(wlT + FRAGW(gq + 4, 0, lane));
  }
  lds_barrier();

  int kc = 0;
  while (true) {
    PSTEP2(kc, 0, 1, bhA, blA, bhB, blB); if (++kc == 32) break;
    PSTEP2(kc, 1, 0, bhB, blB, bhA, blA); if (++kc == 32) break;
  }

  // ---- epilogue: j<2 -> q (half0) in [t][h] / k (half1) in frag order ----
  #pragma unroll
  for (int j = 0; j < 2; ++j) {
    const int g = gq + 4 * j;
    if (half == 0) {                           // q: g in 0..7
      const int ncol = g * 16 + l15;
      #pragma unroll
      for (int mt = 0; mt < 4; ++mt)
        #pragma unroll
        for (int r = 0; r < 4; ++r) {
          const float a = acc[j][mt][r];
          const ushort h = bf16_rne(a);
          const size_t off = (size_t)(m0 + mt * 16 + quad * 4 + r) * H_ + ncol;
          qh[off] = h;
          ql[off] = bf16_rne(a - bf16_tof(h));
        }
    } else {                                   // k: g in 8..15 -> frag order
      const int hcol = (g - 8) * 16 + l15;
      const int kch  = hcol >> 5;
      const int qdh  = (hcol >> 3) & 3;
      const int jj   = hcol & 7;
      #pragma unroll
      for (int mt = 0; mt < 4; ++mt)
        #pragma unroll
        for (int r = 0; r < 4; ++r) {
          const float a = acc[j][mt][r];
          const int tg = m0 + mt * 16 + quad * 4 + r;
          const int bb = tg >> 11, tl = tg & 2047;
          const size_t ad = FRAGK(bb, tl >> 4, kch, qdh * 16 + (tl & 15)) + jj;
          const ushort h = bf16_rne(a);
          kfh[ad] = h;
          kfl[ad] = bf16_rne(a - bf16_tof(h));
        }
    }
  }
  // ---- epilogue: v (both halves, 64 h-cols each) via LDS transpose ----
  __syncthreads();
  {
    ushort* smT = SM;                          // [64][72] local-h x t
    const int lh = wave * 16 + l15;            // 0..63 (local h col)
    #pragma unroll
    for (int mt = 0; mt < 4; ++mt)
      #pragma unroll
      for (int r = 0; r < 4; ++r)
        smT[lh * 72 + mt * 16 + quad * 4 + r] = bf16_rne(acc[2][mt][r]);
    __syncthreads();
    const int bb = m0 >> 11, t0 = m0 & 2047;
    #pragma unroll
    for (int u = 0; u < 2; ++u) {
      const int c    = u * 256 + tid;          // 512 = 4 lht x 2 ktl x 64 lane
      const int lht  = c >> 7;                 // 0..3
      const int ktl  = (c >> 6) & 1;
      const int lv   = c & 63;
      const int qv   = lv >> 4, l15v = lv & 15;
      *(bf16x8*)(vF + FRAGV(bb, half * 4 + lht, (t0 >> 5) + ktl, lv)) =
          *(const bf16x8*)&smT[(lht * 16 + l15v) * 72 + ktl * 32 + qv * 8];
    }
  }
}

// ---------------------------------------------------------------------------
// Kernel 2: block flash attention, split-K (unchanged this round).
// ---------------------------------------------------------------------------
__global__ __launch_bounds__(256) void attn_flash(
    const ushort* __restrict__ qh, const ushort* __restrict__ ql,
    const ushort* __restrict__ kfh, const ushort* __restrict__ kfl,
    const ushort* __restrict__ vF,
    ushort* __restrict__ Opart, float* __restrict__ mlpart)
{
  const int b    = (int)blockIdx.x & 7;        // %8 -> XCD pin
  const int seg  = (int)blockIdx.x >> 3;
  const int qt   = 31 - (int)blockIdx.y;       // heavy first
  const int q0   = qt * 64;
  const int tid  = threadIdx.x;
  const int wave = tid >> 6, lane = tid & 63;
  const int quad = lane >> 4, l15 = lane & 15;
  const f32x4 z4 = (f32x4){0.f, 0.f, 0.f, 0.f};

  __shared__ __align__(16) ushort KhS[4096];   // [s(2)][kc(4)][lane][8] linear
  __shared__ __align__(16) ushort KlS[4096];
  __shared__ __align__(16) ushort VtS[4096];   // [ht(8)][lane][8] linear
  __shared__ __align__(16) ushort smP[4 * 640];

  const int ntiles = 2 * qt + 2;
  const int cnt    = (ntiles + SEG_ - 1) >> 2;
  const int jt0    = seg * cnt;
  const int jt1    = (jt0 + cnt < ntiles) ? (jt0 + cnt) : ntiles;

  const int q0w = q0 + wave * 16;
  const int ntw = ((q0w + 15) >> 5) + 1;
  const size_t pidx = ((size_t)(b * 128 + qt * 4 + wave)) * SEG_ + seg;
  ushort* op = Opart + pidx * 2048;
  float*  ml = mlpart + pidx * 32;

  if (jt0 >= jt1) {
    const bf16x8 zz = {0, 0, 0, 0, 0, 0, 0, 0};
    #pragma unroll
    for (int u = 0; u < 4; ++u)
      *(bf16x8*)(op + lane * 32 + u * 8) = zz;
    if (lane < 32) ml[lane] = (lane & 1) ? 0.f : -1e30f;
    return;
  }

  const size_t base = (size_t)b * T_ * H_;

  const ushort* qhp = qh + base + (size_t)(q0w + l15) * H_ + quad * 8;
  const ushort* qlp = ql + base + (size_t)(q0w + l15) * H_ + quad * 8;
  bf16x8 Qh[4], Ql[4];
  #pragma unroll
  for (int c = 0; c < 4; ++c) {
    Qh[c] = *(const bf16x8*)(qhp + c * 32);
    Ql[c] = *(const bf16x8*)(qlp + c * 32);
  }

  f32x4 O[8];
  #pragma unroll
  for (int i = 0; i < 8; ++i) O[i] = z4;
  float mstate[4] = {-1e30f, -1e30f, -1e30f, -1e30f};
  float lstate[4] = {0.f, 0.f, 0.f, 0.f};

  bf16x8 rkh[2], rkl[2], rv[2];
  {
    #pragma unroll
    for (int u = 0; u < 2; ++u) {
      const int c = u * 256 + tid;
      rkh[u] = *(const bf16x8*)(kfh + FRAGK(b, 2 * jt0 + (c >> 8), (c >> 6) & 3, c & 63));
      rkl[u] = *(const bf16x8*)(kfl + FRAGK(b, 2 * jt0 + (c >> 8), (c >> 6) & 3, c & 63));
      rv[u]  = *(const bf16x8*)(vF  + FRAGV(b, c >> 6, jt0, c & 63));
    }
  }

  for (int jt = jt0; jt < jt1; ++jt) {
    __syncthreads();
    #pragma unroll
    for (int u = 0; u < 2; ++u) {
      const int c = u * 256 + tid;
      *(bf16x8*)&KhS[c * 8] = rkh[u];
      *(bf16x8*)&KlS[c * 8] = rkl[u];
      *(bf16x8*)&VtS[c * 8] = rv[u];
    }
    __syncthreads();

    if (jt + 1 < jt1) {
      #pragma unroll
      for (int u = 0; u < 2; ++u) {
        const int c = u * 256 + tid;
        rkh[u] = *(const bf16x8*)(kfh + FRAGK(b, 2 * (jt + 1) + (c >> 8), (c >> 6) & 3, c & 63));
        rkl[u] = *(const bf16x8*)(kfl + FRAGK(b, 2 * (jt + 1) + (c >> 8), (c >> 6) & 3, c & 63));
        rv[u]  = *(const bf16x8*)(vF  + FRAGV(b, c >> 6, jt + 1, c & 63));
      }
    }

    if (jt < ntw) {
      const int k0 = jt * 32;
      f32x4 shh0 = z4, shh1 = z4, sx0 = z4, sx1 = z4;
      #pragma unroll
      for (int c = 0; c < 4; ++c) {
        const bf16x8 kh0 = *(const bf16x8*)&KhS[(c * 64 + lane) * 8];
        const bf16x8 kh1 = *(const bf16x8*)&KhS[((4 + c) * 64 + lane) * 8];
        const bf16x8 kl0 = *(const bf16x8*)&KlS[(c * 64 + lane) * 8];
        const bf16x8 kl1 = *(const bf16x8*)&KlS[((4 + c) * 64 + lane) * 8];
        shh0 = mfma16(Qh[c], kh0, shh0);
        shh1 = mfma16(Qh[c], kh1, shh1);
        sx0  = mfma16(Qh[c], kl0, sx0);
        sx1  = mfma16(Qh[c], kl1, sx1);
        sx0  = mfma16(Ql[c], kh0, sx0);
        sx1  = mfma16(Ql[c], kh1, sx1);
      }

      float s0[4], s1[4];
      #pragma unroll
      for (int r = 0; r < 4; ++r) {
        s0[r] = (shh0[r] + sx0[r]) * SCALE_;
        s1[r] = (shh1[r] + sx1[r]) * SCALE_;
      }
      if (jt == ntw - 1) {
        const int krel0 = k0 + l15      - q0w - quad * 4;
        const int krel1 = k0 + 16 + l15 - q0w - quad * 4;
        #pragma unroll
        for (int r = 0; r < 4; ++r) {
          if (krel0 > r) s0[r] = -1e30f;
          if (krel1 > r) s1[r] = -1e30f;
        }
      }

      float alpha[4];
      #pragma unroll
      for (int r = 0; r < 4; ++r) {
        const float rm   = rowmax16(fmaxf(s0[r], s1[r]));
        const float mnew = fmaxf(mstate[r], rm);
        alpha[r] = __expf(mstate[r] - mnew);
        mstate[r] = mnew;
        const float p0 = __expf(s0[r] - mnew);
        const float p1 = __expf(s1[r] - mnew);
        lstate[r] = lstate[r] * alpha[r] + rowsum16(p0 + p1);
        smP[wave * 640 + (quad * 4 + r) * 40 + l15]      = bf16_rne(p0);
        smP[wave * 640 + (quad * 4 + r) * 40 + 16 + l15] = bf16_rne(p1);
      }
      #pragma unroll
      for (int ct = 0; ct < 8; ++ct) {
        O[ct][0] *= alpha[0]; O[ct][1] *= alpha[1];
        O[ct][2] *= alpha[2]; O[ct][3] *= alpha[3];
      }
      const bf16x8 pA = *(const bf16x8*)&smP[wave * 640 + l15 * 40 + quad * 8];
      #pragma unroll
      for (int ct = 0; ct < 8; ++ct) {
        const bf16x8 vf = *(const bf16x8*)&VtS[(ct * 64 + lane) * 8];
        O[ct] = mfma16(pA, vf, O[ct]);
      }
    }
  }

  #pragma unroll
  for (int r = 0; r < 4; ++r)
    #pragma unroll
    for (int ct = 0; ct < 8; ++ct)
      op[(quad * 4 + r) * 128 + ct * 16 + l15] = bf16_rne(O[ct][r]);
  if (l15 == 0) {
    #pragma unroll
    for (int r = 0; r < 4; ++r) {
      ml[(quad * 4 + r) * 2]     = mstate[r];
      ml[(quad * 4 + r) * 2 + 1] = lstate[r];
    }
  }
}

// ---------------------------------------------------------------------------
// Kernel 3: combine 4 split-K partials per q-row (unchanged).
// ---------------------------------------------------------------------------
__global__ __launch_bounds__(256) void attn_combine(
    const ushort* __restrict__ Opart, const float* __restrict__ mlpart,
    float* __restrict__ out)
{
  const int idx = blockIdx.x * 256 + threadIdx.x;
  const int c4  = idx & 31;
  const int r   = idx >> 5;
  const int t   = r & 2047;
  const int qt  = t >> 4, r16 = t & 15;
  const size_t pb = ((size_t)((r >> 11) * 128 + qt)) * SEG_;

  float m[SEG_], l[SEG_];
  #pragma unroll
  for (int s = 0; s < SEG_; ++s) {
    m[s] = mlpart[(pb + s) * 32 + r16 * 2];
    l[s] = mlpart[(pb + s) * 32 + r16 * 2 + 1];
  }
  float M = m[0];
  #pragma unroll
  for (int s = 1; s < SEG_; ++s) M = fmaxf(M, m[s]);
  float w[SEG_], L = 0.f;
  #pragma unroll
  for (int s = 0; s < SEG_; ++s) {
    w[s] = __expf(m[s] - M);
    L += l[s] * w[s];
  }
  float4 acc = make_float4(0.f, 0.f, 0.f, 0.f);
  #pragma unroll
  for (int s = 0; s < SEG_; ++s) {
    const ushort4 o = *(const ushort4*)(Opart + (pb + s) * 2048 + r16 * 128 + c4 * 4);
    acc.x += w[s] * bf16_tof(o.x);
    acc.y += w[s] * bf16_tof(o.y);
    acc.z += w[s] * bf16_tof(o.z);
    acc.w += w[s] * bf16_tof(o.w);
  }
  const float inv = 1.0f / L;
  *(float4*)(out + (size_t)r * H_ + c4 * 4) =
      make_float4(acc.x * inv, acc.y * inv, acc.z * inv, acc.w * inv);
}

// ---------------------------------------------------------------------------
extern "C" void kernel_launch(void* const* d_in, const int* in_sizes, int n_in,
                              void* d_out, int out_size, void* d_ws, size_t ws_size,
                              hipStream_t stream) {
  (void)in_sizes; (void)n_in; (void)out_size; (void)ws_size;
  const float* x  = (const float*)d_in[0];
  const float* Wq = (const float*)d_in[1];
  const float* Wk = (const float*)d_in[2];
  const float* Wv = (const float*)d_in[3];
  float* out = (float*)d_out;

  ushort* qhb = (ushort*)d_ws;
  ushort* qlb = qhb + (size_t)M_ * H_;
  ushort* kfh = qlb + (size_t)M_ * H_;
  ushort* kfl = kfh + (size_t)M_ * H_;
  ushort* vFb = kfl + (size_t)M_ * H_;
  ushort* whT = vFb + (size_t)M_ * H_;
  ushort* wlT = whT + (size_t)3 * H_ * E_;
  ushort* Opart = wlT + (size_t)3 * H_ * E_;
  float*  mlpart = (float*)(Opart + (size_t)B_ * 128 * SEG_ * 2048);

  wsplit<<<dim3(192), 256, 0, stream>>>(Wq, Wk, Wv, whT, wlT);
  proj_fused<<<dim3(M_/64, 2), 256, 0, stream>>>(x, whT, wlT,
                                                 qhb, qlb, kfh, kfl, vFb);
  attn_flash<<<dim3(B_*SEG_, 32), 256, 0, stream>>>(qhb, qlb, kfh, kfl, vFb,
                                                    Opart, mlpart);
  attn_combine<<<dim3(2048), 256, 0, stream>>>(Opart, mlpart, out);
}